// Round 2
// baseline (172.472 us; speedup 1.0000x reference)
//
#include <hip/hip_runtime.h>

// MoE: out[b,:] = sum_e softmax(gate(x))[b,e] * (W3_e^T @ relu(W2_e^T @ relu(W1_e^T @ x_b + b1) + b2) + b3)
// Strategy: tokens-as-N MFMA (16x16x32 f16), weights^T as register-resident A-fragments,
// K-permutation pi(q*8+j)=q*4+(j&3)+16*(j>>2) so C/D layout == next layer's B layout in-lane.

typedef _Float16 half_t;
typedef _Float16 half2_t __attribute__((ext_vector_type(2)));
typedef _Float16 half8_t __attribute__((ext_vector_type(8)));
typedef __fp16   fp16v2  __attribute__((ext_vector_type(2)));
typedef float  float4_t __attribute__((ext_vector_type(4)));
typedef float  float2_t __attribute__((ext_vector_type(2)));
typedef int    int4_t   __attribute__((ext_vector_type(4)));

#define MFMA16(A, B, C) __builtin_amdgcn_mfma_f32_16x16x32_f16((A), (B), (C), 0, 0, 0)

static constexpr int E_ = 8, DIN_ = 6, H_ = 32;

union H8U { half2_t h2[4]; half8_t h8; int4_t i4; };
union HI  { half2_t h; int i; };
union PKU { fp16v2 p; half2_t h; };

__device__ __forceinline__ half2_t pkrtz(float a, float b) {
    PKU u; u.p = __builtin_amdgcn_cvt_pkrtz(a, b);
    return u.h;
}

__device__ __forceinline__ half2_t relu2(half2_t v) {
    const half2_t z = {(_Float16)0.0f, (_Float16)0.0f};
    return __builtin_elementwise_max(v, z);
}

__global__ __launch_bounds__(256, 2) void moe_kernel(
    const float* __restrict__ x,  const float* __restrict__ W1, const float* __restrict__ b1,
    const float* __restrict__ W2, const float* __restrict__ b2, const float* __restrict__ W3,
    const float* __restrict__ b3, const float* __restrict__ Wg1, const float* __restrict__ bg1,
    const float* __restrict__ Wg2, const float* __restrict__ bg2,
    float* __restrict__ out, int nTiles, int tilesPerWave)
{
    const int tid  = threadIdx.x;
    const int lane = tid & 63;
    const int t    = lane & 15;   // token slot (B-col n) == A-row (m) index
    const int q    = lane >> 4;   // K-quad
    const int wid  = (int)((blockIdx.x * blockDim.x + tid) >> 6);

    // ---- LDS: f16-packed b2 bias pairs matching the h2 pack order: [e][lane][4 dwords]
    __shared__ __align__(16) int b2pk[E_ * 64 * 4];
    for (int idx = tid; idx < E_ * 64 * 4; idx += blockDim.x) {
        int e  = idx >> 8;
        int ln = (idx >> 2) & 63;
        int k  = idx & 3;
        int qq = ln >> 4;
        int ch = ((k >> 1) << 4) + qq * 4 + ((k & 1) << 1);   // pi-pair base channel
        HI u; u.h = pkrtz(b2[e * H_ + ch], b2[e * H_ + ch + 1]);
        b2pk[idx] = u.i;
    }
    __syncthreads();

    // ---- static A-operand fragments (weights^T, K-permuted). kp=q*8+j -> channel pi(kp).
    half8_t G1[2], G2, W1F[E_][2], W2F[E_][2], W3F[E_];

    #pragma unroll
    for (int f = 0; f < 2; ++f) {          // gate layer1: M=32 hidden -> 2 M-tiles; K slots: 6 x + 1.0(bias) + 0
        H8U u;
        #pragma unroll
        for (int p = 0; p < 4; ++p) {
            int j0 = 2 * p, j1 = 2 * p + 1;
            float v0 = 0.f, v1 = 0.f;
            if (q == 0) {
                v0 = (j0 < DIN_) ? Wg1[j0 * H_ + f * 16 + t] : ((j0 == DIN_) ? bg1[f * 16 + t] : 0.f);
                v1 = (j1 < DIN_) ? Wg1[j1 * H_ + f * 16 + t] : ((j1 == DIN_) ? bg1[f * 16 + t] : 0.f);
            }
            u.h2[p] = pkrtz(v0, v1);
        }
        G1[f] = u.h8;
    }
    {   // gate layer2: M=8 experts padded to 16, K=32 hidden via pi
        H8U u;
        #pragma unroll
        for (int p = 0; p < 4; ++p) {
            int c0 = ((p >> 1) << 4) + q * 4 + ((p & 1) << 1);
            float v0 = (t < E_) ? Wg2[c0 * E_ + t] : 0.f;
            float v1 = (t < E_) ? Wg2[(c0 + 1) * E_ + t] : 0.f;
            u.h2[p] = pkrtz(v0, v1);
        }
        G2 = u.h8;
    }
    #pragma unroll
    for (int e = 0; e < E_; ++e) {
        #pragma unroll
        for (int f = 0; f < 2; ++f) {      // expert layer1 (K slots: 6 x + bias + 0)
            H8U u;
            #pragma unroll
            for (int p = 0; p < 4; ++p) {
                int j0 = 2 * p, j1 = 2 * p + 1;
                float v0 = 0.f, v1 = 0.f;
                if (q == 0) {
                    v0 = (j0 < DIN_) ? W1[(e * DIN_ + j0) * H_ + f * 16 + t]
                                     : ((j0 == DIN_) ? b1[e * H_ + f * 16 + t] : 0.f);
                    v1 = (j1 < DIN_) ? W1[(e * DIN_ + j1) * H_ + f * 16 + t]
                                     : ((j1 == DIN_) ? b1[e * H_ + f * 16 + t] : 0.f);
                }
                u.h2[p] = pkrtz(v0, v1);
            }
            W1F[e][f] = u.h8;
        }
        #pragma unroll
        for (int f = 0; f < 2; ++f) {      // expert layer2, K=32 via pi
            H8U u;
            #pragma unroll
            for (int p = 0; p < 4; ++p) {
                int c0 = ((p >> 1) << 4) + q * 4 + ((p & 1) << 1);
                float v0 = W2[(e * H_ + c0) * H_ + f * 16 + t];
                float v1 = W2[(e * H_ + c0 + 1) * H_ + f * 16 + t];
                u.h2[p] = pkrtz(v0, v1);
            }
            W2F[e][f] = u.h8;
        }
        {   // expert layer3, block-diagonal: rows m=(e',o) nonzero only for e'==e
            H8U u;
            #pragma unroll
            for (int p = 0; p < 4; ++p) {
                int c0 = ((p >> 1) << 4) + q * 4 + ((p & 1) << 1);
                float v0 = 0.f, v1 = 0.f;
                if ((t >> 1) == e) {
                    v0 = W3[(e * H_ + c0) * 2 + (t & 1)];
                    v1 = W3[(e * H_ + c0 + 1) * 2 + (t & 1)];
                }
                u.h2[p] = pkrtz(v0, v1);
            }
            W3F[e] = u.h8;
        }
    }

    // ---- persistent C-init fragments (biases folded into the accumulator init: zero per-tile cost)
    float4_t bg2F, b3F;
    #pragma unroll
    for (int r = 0; r < 4; ++r) {
        int m = q * 4 + r;
        bg2F[r] = (m < E_) ? bg2[m] : 0.f;
        b3F[r]  = b3[m];                 // b3 flat [8][2]: index m=(e,o) directly
    }
    const float4_t zero4 = {0.f, 0.f, 0.f, 0.f};

    // bpermute byte address for gate distribution: pull from lane (q>>1)*16 + t
    const int gsrc = ((((q >> 1) << 4) | t) << 2);

    const int  tile0 = wid * tilesPerWave;
    const bool ldr   = (lane < 16);

    const float* xp = x + ((size_t)tile0 * 16 + t) * DIN_;
    float2_t xa = {0.f, 0.f}, xb = {0.f, 0.f}, xc = {0.f, 0.f};
    if (ldr && tile0 < nTiles) {
        xa = *(const float2_t*)(xp + 0);
        xb = *(const float2_t*)(xp + 2);
        xc = *(const float2_t*)(xp + 4);
    }

    const half2_t one0  = pkrtz(1.f, 0.f);
    const half2_t zeroh = {(_Float16)0.f, (_Float16)0.f};

    for (int it = 0; it < tilesPerWave; ++it) {
        const int tile = tile0 + it;
        if (tile >= nTiles) break;

        // ---- x-augmented B fragment (k=0..5: x, k=6: 1.0 for bias, rest 0; quads>0 all zero)
        H8U ux;
        if (q == 0) {
            ux.h2[0] = pkrtz(xa[0], xa[1]);
            ux.h2[1] = pkrtz(xb[0], xb[1]);
            ux.h2[2] = pkrtz(xc[0], xc[1]);
            ux.h2[3] = one0;
        } else {
            ux.h2[0] = zeroh; ux.h2[1] = zeroh; ux.h2[2] = zeroh; ux.h2[3] = zeroh;
        }
        const half8_t xB = ux.h8;

        // ---- prefetch next tile's x (hides HBM latency behind this tile's compute)
        if (ldr && (it + 1) < tilesPerWave && (tile + 1) < nTiles) {
            const float* xn = xp + (size_t)(it + 1) * 16 * DIN_;
            xa = *(const float2_t*)(xn + 0);
            xb = *(const float2_t*)(xn + 2);
            xc = *(const float2_t*)(xn + 4);
        }

        // ---- gate
        float4_t hgLo = MFMA16(G1[0], xB, zero4);
        float4_t hgHi = MFMA16(G1[1], xB, zero4);
        H8U uh;
        uh.h2[0] = relu2(pkrtz(hgLo[0], hgLo[1]));
        uh.h2[1] = relu2(pkrtz(hgLo[2], hgLo[3]));
        uh.h2[2] = relu2(pkrtz(hgHi[0], hgHi[1]));
        uh.h2[3] = relu2(pkrtz(hgHi[2], hgHi[3]));
        float4_t gl = MFMA16(G2, uh.h8, bg2F);

        // ---- softmax over 8 experts: lane(q=0,t) holds e=0..3, lane(q=1,t) holds e=4..7
        float mx = fmaxf(fmaxf(gl[0], gl[1]), fmaxf(gl[2], gl[3]));
        mx = fmaxf(mx, __shfl_xor(mx, 16));
        const float L2E = 1.44269504f;
        float mk = mx * L2E;
        float ex0 = __builtin_amdgcn_exp2f(gl[0] * L2E - mk);
        float ex1 = __builtin_amdgcn_exp2f(gl[1] * L2E - mk);
        float ex2 = __builtin_amdgcn_exp2f(gl[2] * L2E - mk);
        float ex3 = __builtin_amdgcn_exp2f(gl[3] * L2E - mk);
        float s = (ex0 + ex1) + (ex2 + ex3);
        s += __shfl_xor(s, 16);
        float rs = __builtin_amdgcn_rcpf(s);
        HI pa, pb;
        pa.h = pkrtz(ex0 * rs, ex1 * rs);
        pb.h = pkrtz(ex2 * rs, ex3 * rs);
        int va = __builtin_amdgcn_ds_bpermute(gsrc, pa.i);
        int vb = __builtin_amdgcn_ds_bpermute(gsrc, pb.i);
        HI gsel; gsel.i = (q & 1) ? vb : va;       // lane(q,t) gets g[t,2q], g[t,2q+1]
        float ga = (float)gsel.h[0];
        float gb = (float)gsel.h[1];

        // ---- experts: L1 -> relu/pack -> L2 -> +b2/relu/pack -> L3 accumulate (Y init carries b3)
        float4_t Y = b3F;
        #pragma unroll
        for (int e = 0; e < E_; ++e) {
            float4_t lo = MFMA16(W1F[e][0], xB, zero4);
            float4_t hi = MFMA16(W1F[e][1], xB, zero4);
            H8U u1;
            u1.h2[0] = relu2(pkrtz(lo[0], lo[1]));
            u1.h2[1] = relu2(pkrtz(lo[2], lo[3]));
            u1.h2[2] = relu2(pkrtz(hi[0], hi[1]));
            u1.h2[3] = relu2(pkrtz(hi[2], hi[3]));
            float4_t lo2 = MFMA16(W2F[e][0], u1.h8, zero4);
            float4_t hi2 = MFMA16(W2F[e][1], u1.h8, zero4);
            H8U ub; ub.i4 = *(const int4_t*)&b2pk[(e * 64 + lane) * 4];
            H8U u2;
            u2.h2[0] = relu2(pkrtz(lo2[0], lo2[1]) + ub.h2[0]);
            u2.h2[1] = relu2(pkrtz(lo2[2], lo2[3]) + ub.h2[1]);
            u2.h2[2] = relu2(pkrtz(hi2[0], hi2[1]) + ub.h2[2]);
            u2.h2[3] = relu2(pkrtz(hi2[2], hi2[3]) + ub.h2[3]);
            Y = MFMA16(W3F[e], u2.h8, Y);
        }

        // ---- gated combine: Y rows m=q*4+r are (e=2q+(r>>1), o=r&1); reduce across quads
        float p0 = ga * Y[0] + gb * Y[2];
        float p1 = ga * Y[1] + gb * Y[3];
        p0 += __shfl_xor(p0, 16);
        p0 += __shfl_xor(p0, 32);
        p1 += __shfl_xor(p1, 16);
        p1 += __shfl_xor(p1, 32);
        if (ldr) {
            float2_t o = {p0, p1};
            *(float2_t*)(out + ((size_t)tile * 16 + t) * 2) = o;
        }
    }
}

extern "C" void kernel_launch(void* const* d_in, const int* in_sizes, int n_in,
                              void* d_out, int out_size, void* d_ws, size_t ws_size,
                              hipStream_t stream) {
    const float* x   = (const float*)d_in[0];
    const float* W1  = (const float*)d_in[1];
    const float* b1  = (const float*)d_in[2];
    const float* W2  = (const float*)d_in[3];
    const float* b2  = (const float*)d_in[4];
    const float* W3  = (const float*)d_in[5];
    const float* b3  = (const float*)d_in[6];
    const float* Wg1 = (const float*)d_in[7];
    const float* bg1 = (const float*)d_in[8];
    const float* Wg2 = (const float*)d_in[9];
    const float* bg2 = (const float*)d_in[10];
    float* out = (float*)d_out;

    const int B      = in_sizes[0] / DIN_;
    const int nTiles = (B + 15) / 16;
    const int blocks = 512;                       // 2 blocks/CU, exactly resident at 2 waves/SIMD
    const int nWaves = blocks * (256 / 64);
    const int tpw    = (nTiles + nWaves - 1) / nWaves;

    moe_kernel<<<blocks, 256, 0, stream>>>(x, W1, b1, W2, b2, W3, b3,
                                           Wg1, bg1, Wg2, bg2, out, nTiles, tpw);
}